// Round 15
// baseline (570.932 us; speedup 1.0000x reference)
//
#include <hip/hip_runtime.h>

typedef unsigned short u16;
typedef __attribute__((ext_vector_type(8))) short short8;
typedef __attribute__((ext_vector_type(4))) float f32x4;

#define HDIM 128
#define SCAN_B 512
#define PREP_BLOCKS 572   // (8*16384 + 120*128) / 256, exact

__device__ __forceinline__ float bf2f(u16 v) {
    return __uint_as_float(((unsigned int)v) << 16);
}
__device__ __forceinline__ u16 f2bf(float f) {
    unsigned int u = __float_as_uint(f);
    unsigned int r = (u + 0x7FFFu + ((u >> 16) & 1u)) >> 16;  // RNE
    return (u16)r;
}

// ---- prep (572 blocks): transpose+bf16 8 weight mats + bf16 embed table
//      + deg histogram (remaining blocks). deg must be zeroed beforehand.
__global__ __launch_bounds__(256) void prep_hist_kernel(
    const float* __restrict__ w1, const float* __restrict__ w2,
    const float* __restrict__ pw1, const float* __restrict__ pw2,
    const float* __restrict__ atom_emb,
    u16* __restrict__ wt, u16* __restrict__ ebf,
    const int* __restrict__ edges, int* __restrict__ deg, int E, int N)
{
    if (blockIdx.x < PREP_BLOCKS) {
        int gid = blockIdx.x * 256 + threadIdx.x;
        if (gid < 8 * 16384) {
            int mat = gid >> 14;
            int idx = gid & 16383;
            int n = idx >> 7, k = idx & 127;
            const float* src;
            if      (mat < 3) src = w1 + mat * 16384;
            else if (mat < 6) src = w2 + (mat - 3) * 16384;
            else if (mat == 6) src = pw1;
            else               src = pw2;
            wt[gid] = f2bf(src[k * 128 + n]);
        } else {
            int i = gid - 8 * 16384;
            ebf[i] = f2bf(atom_emb[i]);   // exactly 120*128 remaining
        }
    } else {
        int e = (blockIdx.x - PREP_BLOCKS) * 256 + threadIdx.x;
        if (e >= E) return;
        int d = edges[E + e];
        d = d < 0 ? 0 : (d >= N ? N - 1 : d);
        atomicAdd(&deg[d], 1);
    }
}

__global__ __launch_bounds__(SCAN_B) void scan_block_kernel(
    const int* __restrict__ deg, int* __restrict__ offs, int* __restrict__ bsum, int N)
{
    __shared__ int tmp[SCAN_B];
    int t = threadIdx.x;
    int gid = blockIdx.x * SCAN_B + t;
    int v = (gid < N) ? deg[gid] : 0;
    tmp[t] = v;
    __syncthreads();
#pragma unroll
    for (int off = 1; off < SCAN_B; off <<= 1) {
        int add = (t >= off) ? tmp[t - off] : 0;
        __syncthreads();
        tmp[t] += add;
        __syncthreads();
    }
    if (gid < N) offs[gid] = tmp[t] - v;           // exclusive within block
    if (t == SCAN_B - 1) bsum[blockIdx.x] = tmp[t]; // raw block total
}

// finalize: block-uniform prefix + cursor init + graph-boundary array
__global__ __launch_bounds__(256) void finalize_offs_kernel(
    int* __restrict__ offs, const int* __restrict__ bsum,
    int* __restrict__ cursor, const int* __restrict__ nb,
    int* __restrict__ gbounds, int N, int E, int G)
{
    __shared__ int red[256];
    const int tid = threadIdx.x;
    const int B = blockIdx.x >> 1;   // SCAN_B=512, block=256
    int sum = 0;
    for (int t = tid; t < B; t += 256) sum += bsum[t];
    red[tid] = sum;
    __syncthreads();
#pragma unroll
    for (int off = 128; off > 0; off >>= 1) {
        if (tid < off) red[tid] += red[tid + off];
        __syncthreads();
    }
    int prefix = red[0];
    int gid = blockIdx.x * 256 + tid;
    if (gid < N) {
        int v = offs[gid] + prefix;
        offs[gid] = v;
        cursor[gid] = v;
        int cur = nb[gid]; cur = cur < 0 ? 0 : (cur > G - 1 ? G - 1 : cur);
        if (gid == 0) {
            for (int g = 0; g <= cur; g++) gbounds[g] = 0;
        } else {
            int prev = nb[gid - 1]; prev = prev < 0 ? 0 : (prev > G - 1 ? G - 1 : prev);
            for (int g = prev + 1; g <= cur; g++) gbounds[g] = gid;
        }
        if (gid == N - 1) {
            for (int g = cur + 1; g <= G; g++) gbounds[g] = N;
        }
    }
    if (gid == 0) offs[N] = E;
}

__global__ __launch_bounds__(256) void fill_csr_kernel(
    const int* __restrict__ edges, const int* __restrict__ etypes,
    int* __restrict__ cursor, int* __restrict__ csr, int E, int N)
{
    int e = blockIdx.x * 256 + threadIdx.x;
    if (e >= E) return;
    int s = edges[e], d = edges[E + e], t = etypes[e];
    s = s < 0 ? 0 : (s >= N ? N - 1 : s);
    d = d < 0 ? 0 : (d >= N ? N - 1 : d);
    t = t < 0 ? 0 : (t > 4 ? 4 : t);
    int pos = atomicAdd(&cursor[d], 1);
    csr[pos] = (s << 3) | t;
}

// ============ agg: xa = bf16(x + sum relu(x[src]+bond)), standalone, max-occupancy ============
// 4 rows lockstep per rp, k-unroll 2 (8 gathers in flight). LDS = bond table only (1.25 KB)
// -> occupancy limited by VGPR cap 64 (launch_bounds 512,8) = 32 waves/CU, 2x the fused form.
__global__ __launch_bounds__(512, 8) void agg_kernel(
    const u16* __restrict__ x_in, u16* __restrict__ xa,
    const int* __restrict__ types, int use_emb, const u16* __restrict__ ebf,
    const int* __restrict__ offs, const int* __restrict__ csr,
    const float* __restrict__ bond_emb, int N)
{
    __shared__ __align__(16) u16 bsh[5 * 128];
    const int tid  = threadIdx.x;
    const int row0 = blockIdx.x * 128;
    for (int i = tid; i < 640; i += 512) bsh[i] = f2bf(bond_emb[i]);
    const int rp = tid >> 4, c8 = (tid & 15) * 8;
    __syncthreads();

    int rowA = row0 + rp,      rowB = row0 + 32 + rp;
    int rowC = row0 + 64 + rp, rowD = row0 + 96 + rp;
    int rcA = rowA < N ? rowA : N - 1;
    int rcB = rowB < N ? rowB : N - 1;
    int rcC = rowC < N ? rowC : N - 1;
    int rcD = rowD < N ? rowD : N - 1;
    const u16 *spA, *spB, *spC, *spD;
    if (use_emb) {
        int tA = types[rcA]; tA = tA < 0 ? 0 : (tA > 119 ? 119 : tA);
        int tB = types[rcB]; tB = tB < 0 ? 0 : (tB > 119 ? 119 : tB);
        int tC = types[rcC]; tC = tC < 0 ? 0 : (tC > 119 ? 119 : tC);
        int tD = types[rcD]; tD = tD < 0 ? 0 : (tD > 119 ? 119 : tD);
        spA = ebf + (size_t)tA * 128; spB = ebf + (size_t)tB * 128;
        spC = ebf + (size_t)tC * 128; spD = ebf + (size_t)tD * 128;
    } else {
        spA = x_in + (size_t)rcA * 128; spB = x_in + (size_t)rcB * 128;
        spC = x_in + (size_t)rcC * 128; spD = x_in + (size_t)rcD * 128;
    }
    int jbA = offs[rcA], jeA = rowA < N ? offs[rcA + 1] : jbA;
    int jbB = offs[rcB], jeB = rowB < N ? offs[rcB + 1] : jbB;
    int jbC = offs[rcC], jeC = rowC < N ? offs[rcC + 1] : jbC;
    int jbD = offs[rcD], jeD = rowD < N ? offs[rcD + 1] : jbD;
    uint4 svA = *(const uint4*)(spA + c8);
    uint4 svB = *(const uint4*)(spB + c8);
    uint4 svC = *(const uint4*)(spC + c8);
    uint4 svD = *(const uint4*)(spD + c8);
    float accA[8], accB[8], accC[8], accD[8];
    {
        const u16* pA = (const u16*)&svA; const u16* pB = (const u16*)&svB;
        const u16* pC = (const u16*)&svC; const u16* pD = (const u16*)&svD;
#pragma unroll
        for (int i = 0; i < 8; i++) {
            accA[i] = bf2f(pA[i]); accB[i] = bf2f(pB[i]);
            accC[i] = bf2f(pC[i]); accD[i] = bf2f(pD[i]);
        }
    }
    int dA = jeA - jbA, dB = jeB - jbB, dC = jeC - jbC, dD = jeD - jbD;
    int dmax = dA > dB ? dA : dB;
    dmax = dC > dmax ? dC : dmax;
    dmax = dD > dmax ? dD : dmax;
    for (int k = 0; k < dmax; k += 2) {
        bool a0 = k < dA,     a1 = (k + 1) < dA;
        bool a2 = k < dB,     a3 = (k + 1) < dB;
        bool a4 = k < dC,     a5 = (k + 1) < dC;
        bool a6 = k < dD,     a7 = (k + 1) < dD;
        int v0 = a0 ? csr[jbA + k] : 0;  int v1 = a1 ? csr[jbA + k + 1] : 0;
        int v2 = a2 ? csr[jbB + k] : 0;  int v3 = a3 ? csr[jbB + k + 1] : 0;
        int v4 = a4 ? csr[jbC + k] : 0;  int v5 = a5 ? csr[jbC + k + 1] : 0;
        int v6 = a6 ? csr[jbD + k] : 0;  int v7 = a7 ? csr[jbD + k + 1] : 0;
        const u16 *p0, *p1, *p2, *p3, *p4, *p5, *p6, *p7;
        if (use_emb) {
            int t0 = types[v0 >> 3]; t0 = t0 < 0 ? 0 : (t0 > 119 ? 119 : t0);
            int t1 = types[v1 >> 3]; t1 = t1 < 0 ? 0 : (t1 > 119 ? 119 : t1);
            int t2 = types[v2 >> 3]; t2 = t2 < 0 ? 0 : (t2 > 119 ? 119 : t2);
            int t3 = types[v3 >> 3]; t3 = t3 < 0 ? 0 : (t3 > 119 ? 119 : t3);
            int t4 = types[v4 >> 3]; t4 = t4 < 0 ? 0 : (t4 > 119 ? 119 : t4);
            int t5 = types[v5 >> 3]; t5 = t5 < 0 ? 0 : (t5 > 119 ? 119 : t5);
            int t6 = types[v6 >> 3]; t6 = t6 < 0 ? 0 : (t6 > 119 ? 119 : t6);
            int t7 = types[v7 >> 3]; t7 = t7 < 0 ? 0 : (t7 > 119 ? 119 : t7);
            p0 = ebf + (size_t)t0 * 128; p1 = ebf + (size_t)t1 * 128;
            p2 = ebf + (size_t)t2 * 128; p3 = ebf + (size_t)t3 * 128;
            p4 = ebf + (size_t)t4 * 128; p5 = ebf + (size_t)t5 * 128;
            p6 = ebf + (size_t)t6 * 128; p7 = ebf + (size_t)t7 * 128;
        } else {
            p0 = x_in + (size_t)(v0 >> 3) * 128; p1 = x_in + (size_t)(v1 >> 3) * 128;
            p2 = x_in + (size_t)(v2 >> 3) * 128; p3 = x_in + (size_t)(v3 >> 3) * 128;
            p4 = x_in + (size_t)(v4 >> 3) * 128; p5 = x_in + (size_t)(v5 >> 3) * 128;
            p6 = x_in + (size_t)(v6 >> 3) * 128; p7 = x_in + (size_t)(v7 >> 3) * 128;
        }
        uint4 g0 = *(const uint4*)(p0 + c8);
        uint4 g1 = *(const uint4*)(p1 + c8);
        uint4 g2 = *(const uint4*)(p2 + c8);
        uint4 g3 = *(const uint4*)(p3 + c8);
        uint4 g4 = *(const uint4*)(p4 + c8);
        uint4 g5 = *(const uint4*)(p5 + c8);
        uint4 g6 = *(const uint4*)(p6 + c8);
        uint4 g7 = *(const uint4*)(p7 + c8);
        if (a0) { const u16* gp = (const u16*)&g0; const u16* bp = bsh + (v0 & 7) * 128 + c8;
#pragma unroll
            for (int i = 0; i < 8; i++) { float mm = bf2f(gp[i]) + bf2f(bp[i]); accA[i] += mm > 0.f ? mm : 0.f; } }
        if (a1) { const u16* gp = (const u16*)&g1; const u16* bp = bsh + (v1 & 7) * 128 + c8;
#pragma unroll
            for (int i = 0; i < 8; i++) { float mm = bf2f(gp[i]) + bf2f(bp[i]); accA[i] += mm > 0.f ? mm : 0.f; } }
        if (a2) { const u16* gp = (const u16*)&g2; const u16* bp = bsh + (v2 & 7) * 128 + c8;
#pragma unroll
            for (int i = 0; i < 8; i++) { float mm = bf2f(gp[i]) + bf2f(bp[i]); accB[i] += mm > 0.f ? mm : 0.f; } }
        if (a3) { const u16* gp = (const u16*)&g3; const u16* bp = bsh + (v3 & 7) * 128 + c8;
#pragma unroll
            for (int i = 0; i < 8; i++) { float mm = bf2f(gp[i]) + bf2f(bp[i]); accB[i] += mm > 0.f ? mm : 0.f; } }
        if (a4) { const u16* gp = (const u16*)&g4; const u16* bp = bsh + (v4 & 7) * 128 + c8;
#pragma unroll
            for (int i = 0; i < 8; i++) { float mm = bf2f(gp[i]) + bf2f(bp[i]); accC[i] += mm > 0.f ? mm : 0.f; } }
        if (a5) { const u16* gp = (const u16*)&g5; const u16* bp = bsh + (v5 & 7) * 128 + c8;
#pragma unroll
            for (int i = 0; i < 8; i++) { float mm = bf2f(gp[i]) + bf2f(bp[i]); accC[i] += mm > 0.f ? mm : 0.f; } }
        if (a6) { const u16* gp = (const u16*)&g6; const u16* bp = bsh + (v6 & 7) * 128 + c8;
#pragma unroll
            for (int i = 0; i < 8; i++) { float mm = bf2f(gp[i]) + bf2f(bp[i]); accD[i] += mm > 0.f ? mm : 0.f; } }
        if (a7) { const u16* gp = (const u16*)&g7; const u16* bp = bsh + (v7 & 7) * 128 + c8;
#pragma unroll
            for (int i = 0; i < 8; i++) { float mm = bf2f(gp[i]) + bf2f(bp[i]); accD[i] += mm > 0.f ? mm : 0.f; } }
    }
    uint4 ovA, ovB, ovC, ovD;
    {
        u16* op;
        op = (u16*)&ovA;
#pragma unroll
        for (int i = 0; i < 8; i++) op[i] = f2bf(accA[i]);
        op = (u16*)&ovB;
#pragma unroll
        for (int i = 0; i < 8; i++) op[i] = f2bf(accB[i]);
        op = (u16*)&ovC;
#pragma unroll
        for (int i = 0; i < 8; i++) op[i] = f2bf(accC[i]);
        op = (u16*)&ovD;
#pragma unroll
        for (int i = 0; i < 8; i++) op[i] = f2bf(accD[i]);
    }
    if (rowA < N) *(uint4*)(xa + (size_t)rowA * 128 + c8) = ovA;
    if (rowB < N) *(uint4*)(xa + (size_t)rowB * 128 + c8) = ovB;
    if (rowC < N) *(uint4*)(xa + (size_t)rowC * 128 + c8) = ovC;
    if (rowD < N) *(uint4*)(xa + (size_t)rowD * 128 + c8) = ovD;
}

// ============ mlp: x_out = relu(xa @ W1 + b1) @ W2 + b2, 128 rows/block, 512 threads ============
__global__ __launch_bounds__(512, 4) void mlp_kernel(
    const u16* __restrict__ xa, u16* __restrict__ x_out,
    const u16* __restrict__ w1t, const float* __restrict__ b1,
    const u16* __restrict__ w2t, const float* __restrict__ b2, int N)
{
    __shared__ __align__(16) u16 As[128][136];
    __shared__ __align__(16) u16 Ws[128][136];
    const int tid  = threadIdx.x;
    const int row0 = blockIdx.x * 128;
    const int wave = tid >> 6, lane = tid & 63;
    const int m = lane & 15, quad = lane >> 4;

    {
        const uint4* src = (const uint4*)w1t;
        for (int i = tid; i < 2048; i += 512) {
            int n = i >> 4, k8 = i & 15;
            *(uint4*)&Ws[n][k8 * 8] = src[i];
        }
    }
    for (int i = tid; i < 2048; i += 512) {
        int r = i >> 4, c8 = (i & 15) * 8;
        int row = row0 + r;
        uint4 ov = make_uint4(0u, 0u, 0u, 0u);
        if (row < N) ov = *(const uint4*)(xa + (size_t)row * 128 + c8);
        *(uint4*)&As[r][c8] = ov;
    }
    __syncthreads();

    f32x4 acc[8];
#pragma unroll
    for (int c = 0; c < 8; c++) acc[c] = (f32x4){0.f, 0.f, 0.f, 0.f};
#pragma unroll
    for (int q = 0; q < 4; q++) {
        short8 a = *(const short8*)&As[wave * 16 + m][q * 32 + quad * 8];
#pragma unroll
        for (int c = 0; c < 8; c++) {
            short8 b = *(const short8*)&Ws[c * 16 + m][q * 32 + quad * 8];
            acc[c] = __builtin_amdgcn_mfma_f32_16x16x32_bf16(a, b, acc[c], 0, 0, 0);
        }
    }
    __syncthreads();
    {
        const uint4* src = (const uint4*)w2t;
        for (int i = tid; i < 2048; i += 512) {
            int n = i >> 4, k8 = i & 15;
            *(uint4*)&Ws[n][k8 * 8] = src[i];
        }
    }
#pragma unroll
    for (int c = 0; c < 8; c++) {
        int col = c * 16 + m;
        float bias = b1[col];
#pragma unroll
        for (int r = 0; r < 4; r++) {
            float v = acc[c][r] + bias;
            v = v > 0.f ? v : 0.f;
            As[wave * 16 + quad * 4 + r][col] = f2bf(v);
        }
    }
    __syncthreads();
    f32x4 acc2[8];
#pragma unroll
    for (int c = 0; c < 8; c++) acc2[c] = (f32x4){0.f, 0.f, 0.f, 0.f};
#pragma unroll
    for (int q = 0; q < 4; q++) {
        short8 a = *(const short8*)&As[wave * 16 + m][q * 32 + quad * 8];
#pragma unroll
        for (int c = 0; c < 8; c++) {
            short8 b = *(const short8*)&Ws[c * 16 + m][q * 32 + quad * 8];
            acc2[c] = __builtin_amdgcn_mfma_f32_16x16x32_bf16(a, b, acc2[c], 0, 0, 0);
        }
    }
    __syncthreads();
#pragma unroll
    for (int c = 0; c < 8; c++) {
        int col = c * 16 + m;
        float bias = b2[col];
#pragma unroll
        for (int r = 0; r < 4; r++)
            As[wave * 16 + quad * 4 + r][col] = f2bf(acc2[c][r] + bias);
    }
    __syncthreads();
    for (int i = tid; i < 2048; i += 512) {
        int r = i >> 4, c8 = (i & 15) * 8;
        int row = row0 + r;
        if (row < N) *(uint4*)(x_out + (size_t)row * 128 + c8) = *(const uint4*)&As[r][c8];
    }
}

// ---- readout mean: bounds precomputed
__global__ __launch_bounds__(256) void readout_mean_kernel(
    const u16* __restrict__ x, const int* __restrict__ gbounds,
    u16* __restrict__ gm, int N)
{
    __shared__ float part[16][128];
    int b = blockIdx.x;
    int tid = threadIdx.x;
    int s = gbounds[b], e = gbounds[b + 1];
    int rg = tid >> 4, c8 = (tid & 15) * 8;
    float acc[8];
#pragma unroll
    for (int i = 0; i < 8; i++) acc[i] = 0.f;
    for (int n = s + rg; n < e; n += 16) {
        uint4 v = *(const uint4*)(x + (size_t)n * 128 + c8);
        const u16* vp = (const u16*)&v;
#pragma unroll
        for (int i = 0; i < 8; i++) acc[i] += bf2f(vp[i]);
    }
#pragma unroll
    for (int i = 0; i < 8; i++) part[rg][c8 + i] = acc[i];
    __syncthreads();
    if (tid < 128) {
        float sum = 0.f;
#pragma unroll
        for (int g = 0; g < 16; g++) sum += part[g][tid];
        float cnt = (float)((e - s) > 0 ? (e - s) : 1);
        gm[(size_t)b * 128 + tid] = f2bf(sum / cnt);
    }
}

// ---- proj: out = silu(gm @ PW1 + pb1) @ PW2 + pb2   (fp32 out, 64 rows/block)
__global__ __launch_bounds__(256) void proj_kernel(
    const u16* __restrict__ gm, float* __restrict__ out,
    const u16* __restrict__ pw1t, const float* __restrict__ pb1,
    const u16* __restrict__ pw2t, const float* __restrict__ pb2, int G)
{
    __shared__ __align__(16) u16 As[64][136];
    __shared__ __align__(16) u16 Ws[128][136];
    const int tid  = threadIdx.x;
    const int row0 = blockIdx.x * 64;
    const int wave = tid >> 6, lane = tid & 63;
    const int m = lane & 15, quad = lane >> 4;

    {
        const uint4* src = (const uint4*)pw1t;
        for (int i = tid; i < 2048; i += 256) {
            int n = i >> 4, k8 = i & 15;
            *(uint4*)&Ws[n][k8 * 8] = src[i];
        }
    }
    for (int i = tid; i < 1024; i += 256) {
        int r = i >> 4, c8 = (i & 15) * 8;
        int row = row0 + r;
        uint4 ov = make_uint4(0u, 0u, 0u, 0u);
        if (row < G) ov = *(const uint4*)(gm + (size_t)row * 128 + c8);
        *(uint4*)&As[r][c8] = ov;
    }
    __syncthreads();
    f32x4 acc[8];
#pragma unroll
    for (int c = 0; c < 8; c++) acc[c] = (f32x4){0.f, 0.f, 0.f, 0.f};
#pragma unroll
    for (int q = 0; q < 4; q++) {
        short8 a = *(const short8*)&As[wave * 16 + m][q * 32 + quad * 8];
#pragma unroll
        for (int c = 0; c < 8; c++) {
            short8 b = *(const short8*)&Ws[c * 16 + m][q * 32 + quad * 8];
            acc[c] = __builtin_amdgcn_mfma_f32_16x16x32_bf16(a, b, acc[c], 0, 0, 0);
        }
    }
    __syncthreads();
    {
        const uint4* src = (const uint4*)pw2t;
        for (int i = tid; i < 2048; i += 256) {
            int n = i >> 4, k8 = i & 15;
            *(uint4*)&Ws[n][k8 * 8] = src[i];
        }
    }
#pragma unroll
    for (int c = 0; c < 8; c++) {
        int col = c * 16 + m;
        float bias = pb1[col];
#pragma unroll
        for (int r = 0; r < 4; r++) {
            float v = acc[c][r] + bias;
            v = v / (1.f + __expf(-v));   // SiLU
            As[wave * 16 + quad * 4 + r][col] = f2bf(v);
        }
    }
    __syncthreads();
    f32x4 acc2[8];
#pragma unroll
    for (int c = 0; c < 8; c++) acc2[c] = (f32x4){0.f, 0.f, 0.f, 0.f};
#pragma unroll
    for (int q = 0; q < 4; q++) {
        short8 a = *(const short8*)&As[wave * 16 + m][q * 32 + quad * 8];
#pragma unroll
        for (int c = 0; c < 8; c++) {
            short8 b = *(const short8*)&Ws[c * 16 + m][q * 32 + quad * 8];
            acc2[c] = __builtin_amdgcn_mfma_f32_16x16x32_bf16(a, b, acc2[c], 0, 0, 0);
        }
    }
#pragma unroll
    for (int c = 0; c < 8; c++) {
        int col = c * 16 + m;
        float bias = pb2[col];
#pragma unroll
        for (int r = 0; r < 4; r++) {
            int row = row0 + wave * 16 + quad * 4 + r;
            if (row < G) out[(size_t)row * 128 + col] = acc2[c][r] + bias;
        }
    }
}

extern "C" void kernel_launch(void* const* d_in, const int* in_sizes, int n_in,
                              void* d_out, int out_size, void* d_ws, size_t ws_size,
                              hipStream_t stream) {
    const int*   atom_types  = (const int*)d_in[0];
    const int*   edges       = (const int*)d_in[1];
    const int*   edge_types  = (const int*)d_in[2];
    const int*   node_batch  = (const int*)d_in[3];
    const float* atom_emb    = (const float*)d_in[4];
    const float* bond_emb    = (const float*)d_in[5];
    const float* conv_w1     = (const float*)d_in[6];
    const float* conv_b1     = (const float*)d_in[7];
    const float* conv_w2     = (const float*)d_in[8];
    const float* conv_b2     = (const float*)d_in[9];
    const float* pw1         = (const float*)d_in[10];
    const float* pb1         = (const float*)d_in[11];
    const float* pw2         = (const float*)d_in[12];
    const float* pb2         = (const float*)d_in[13];
    float* out = (float*)d_out;

    const int N = in_sizes[0];
    const int E = in_sizes[2];
    const int G = out_size / HDIM;
    const int nblk = (N + SCAN_B - 1) / SCAN_B;

    size_t xA_bytes  = (size_t)N * HDIM * sizeof(u16);
    size_t xB_bytes  = (size_t)N * HDIM * sizeof(u16);
    size_t wt_bytes  = (size_t)8 * HDIM * HDIM * sizeof(u16);
    size_t ebf_bytes = (size_t)120 * HDIM * sizeof(u16);
    size_t gm_bytes  = (size_t)G * HDIM * sizeof(u16);
    size_t deg_bytes = (size_t)N * 4;
    size_t off_bytes = (size_t)(N + 1) * 4;
    size_t cur_bytes = (size_t)N * 4;
    size_t bs_bytes  = (size_t)nblk * 4;
    size_t gb_bytes  = (size_t)(G + 1) * 4;
    size_t csr_bytes = (size_t)E * 4;
    size_t need = xA_bytes + xB_bytes + wt_bytes + ebf_bytes + gm_bytes +
                  deg_bytes + off_bytes + cur_bytes + bs_bytes + gb_bytes + csr_bytes;
    if (ws_size < need) {
        hipMemsetAsync(d_out, 0, (size_t)out_size * sizeof(float), stream);
        return;
    }
    char* p = (char*)d_ws;
    u16* xA     = (u16*)p;  p += xA_bytes;
    u16* xB     = (u16*)p;  p += xB_bytes;
    u16* wt     = (u16*)p;  p += wt_bytes;
    u16* ebf    = (u16*)p;  p += ebf_bytes;
    u16* gm     = (u16*)p;  p += gm_bytes;
    int* deg    = (int*)p;  p += deg_bytes;
    int* offs   = (int*)p;  p += off_bytes;
    int* cur    = (int*)p;  p += cur_bytes;
    int* bsum   = (int*)p;  p += bs_bytes;
    int* gbound = (int*)p;  p += gb_bytes;
    int* csr    = (int*)p;

    hipMemsetAsync(deg, 0, deg_bytes, stream);
    prep_hist_kernel<<<PREP_BLOCKS + (E + 255) / 256, 256, 0, stream>>>(
        conv_w1, conv_w2, pw1, pw2, atom_emb, wt, ebf, edges, deg, E, N);
    scan_block_kernel<<<nblk, SCAN_B, 0, stream>>>(deg, offs, bsum, N);
    finalize_offs_kernel<<<(N + 255) / 256, 256, 0, stream>>>(
        offs, bsum, cur, node_batch, gbound, N, E, G);
    fill_csr_kernel<<<(E + 255) / 256, 256, 0, stream>>>(edges, edge_types, cur, csr, E, N);

    const int gblocks = (N + 127) / 128;
    // layer l: agg (x -> xB as scratch), mlp (xB -> x). x lives in xA.
    // layer 0 reads the virtual embedding table instead of xA.
    agg_kernel<<<gblocks, 512, 0, stream>>>(
        xA /*unused*/, xB, atom_types, 1, ebf, offs, csr, bond_emb, N);
    mlp_kernel<<<gblocks, 512, 0, stream>>>(
        xB, xA, wt + 0 * 16384, conv_b1 + 0, wt + 3 * 16384, conv_b2 + 0, N);
    agg_kernel<<<gblocks, 512, 0, stream>>>(
        xA, xB, atom_types, 0, ebf, offs, csr, bond_emb, N);
    mlp_kernel<<<gblocks, 512, 0, stream>>>(
        xB, xA, wt + 1 * 16384, conv_b1 + 128, wt + 4 * 16384, conv_b2 + 128, N);
    agg_kernel<<<gblocks, 512, 0, stream>>>(
        xA, xB, atom_types, 0, ebf, offs, csr, bond_emb, N);
    mlp_kernel<<<gblocks, 512, 0, stream>>>(
        xB, xA, wt + 2 * 16384, conv_b1 + 256, wt + 5 * 16384, conv_b2 + 256, N);

    readout_mean_kernel<<<G, 256, 0, stream>>>(xA, gbound, gm, N);
    proj_kernel<<<(G + 63) / 64, 256, 0, stream>>>(
        gm, out, wt + 6 * 16384, pb1, wt + 7 * 16384, pb2, G);
}

// Round 16
// 341.800 us; speedup vs baseline: 1.6704x; 1.6704x over previous
//
#include <hip/hip_runtime.h>

typedef unsigned short u16;
typedef __attribute__((ext_vector_type(8))) short short8;
typedef __attribute__((ext_vector_type(4))) float f32x4;

#define HDIM 128
#define SCAN_B 512
#define CSH 2048          // per-block LDS CSR cache entries
#define PREP_BLOCKS 572   // (8*16384 + 120*128) / 256, exact

__device__ __forceinline__ float bf2f(u16 v) {
    return __uint_as_float(((unsigned int)v) << 16);
}
__device__ __forceinline__ u16 f2bf(float f) {
    unsigned int u = __float_as_uint(f);
    unsigned int r = (u + 0x7FFFu + ((u >> 16) & 1u)) >> 16;  // RNE
    return (u16)r;
}

// ---- prep (572 blocks): transpose+bf16 8 weight mats + bf16 embed table
//      + deg histogram (remaining blocks). deg must be zeroed beforehand.
__global__ __launch_bounds__(256) void prep_hist_kernel(
    const float* __restrict__ w1, const float* __restrict__ w2,
    const float* __restrict__ pw1, const float* __restrict__ pw2,
    const float* __restrict__ atom_emb,
    u16* __restrict__ wt, u16* __restrict__ ebf,
    const int* __restrict__ edges, int* __restrict__ deg, int E, int N)
{
    if (blockIdx.x < PREP_BLOCKS) {
        int gid = blockIdx.x * 256 + threadIdx.x;
        if (gid < 8 * 16384) {
            int mat = gid >> 14;
            int idx = gid & 16383;
            int n = idx >> 7, k = idx & 127;
            const float* src;
            if      (mat < 3) src = w1 + mat * 16384;
            else if (mat < 6) src = w2 + (mat - 3) * 16384;
            else if (mat == 6) src = pw1;
            else               src = pw2;
            wt[gid] = f2bf(src[k * 128 + n]);
        } else {
            int i = gid - 8 * 16384;
            ebf[i] = f2bf(atom_emb[i]);   // exactly 120*128 remaining
        }
    } else {
        int e = (blockIdx.x - PREP_BLOCKS) * 256 + threadIdx.x;
        if (e >= E) return;
        int d = edges[E + e];
        d = d < 0 ? 0 : (d >= N ? N - 1 : d);
        atomicAdd(&deg[d], 1);
    }
}

__global__ __launch_bounds__(SCAN_B) void scan_block_kernel(
    const int* __restrict__ deg, int* __restrict__ offs, int* __restrict__ bsum, int N)
{
    __shared__ int tmp[SCAN_B];
    int t = threadIdx.x;
    int gid = blockIdx.x * SCAN_B + t;
    int v = (gid < N) ? deg[gid] : 0;
    tmp[t] = v;
    __syncthreads();
#pragma unroll
    for (int off = 1; off < SCAN_B; off <<= 1) {
        int add = (t >= off) ? tmp[t - off] : 0;
        __syncthreads();
        tmp[t] += add;
        __syncthreads();
    }
    if (gid < N) offs[gid] = tmp[t] - v;           // exclusive within block
    if (t == SCAN_B - 1) bsum[blockIdx.x] = tmp[t]; // raw block total
}

// finalize: block-uniform prefix + cursor init + graph-boundary array
// gbounds[g] = lower_bound(nb, g); gbounds[G] = N (nb is sorted).
__global__ __launch_bounds__(256) void finalize_offs_kernel(
    int* __restrict__ offs, const int* __restrict__ bsum,
    int* __restrict__ cursor, const int* __restrict__ nb,
    int* __restrict__ gbounds, int N, int E, int G)
{
    __shared__ int red[256];
    const int tid = threadIdx.x;
    const int B = blockIdx.x >> 1;   // SCAN_B=512, block=256
    int sum = 0;
    for (int t = tid; t < B; t += 256) sum += bsum[t];
    red[tid] = sum;
    __syncthreads();
#pragma unroll
    for (int off = 128; off > 0; off >>= 1) {
        if (tid < off) red[tid] += red[tid + off];
        __syncthreads();
    }
    int prefix = red[0];
    int gid = blockIdx.x * 256 + tid;
    if (gid < N) {
        int v = offs[gid] + prefix;
        offs[gid] = v;
        cursor[gid] = v;
        // graph boundary fill (nb sorted; clamp defensively)
        int cur = nb[gid]; cur = cur < 0 ? 0 : (cur > G - 1 ? G - 1 : cur);
        if (gid == 0) {
            for (int g = 0; g <= cur; g++) gbounds[g] = 0;
        } else {
            int prev = nb[gid - 1]; prev = prev < 0 ? 0 : (prev > G - 1 ? G - 1 : prev);
            for (int g = prev + 1; g <= cur; g++) gbounds[g] = gid;
        }
        if (gid == N - 1) {
            for (int g = cur + 1; g <= G; g++) gbounds[g] = N;
        }
    }
    if (gid == 0) offs[N] = E;
}

__global__ __launch_bounds__(256) void fill_csr_kernel(
    const int* __restrict__ edges, const int* __restrict__ etypes,
    int* __restrict__ cursor, int* __restrict__ csr, int E, int N)
{
    int e = blockIdx.x * 256 + threadIdx.x;
    if (e >= E) return;
    int s = edges[e], d = edges[E + e], t = etypes[e];
    s = s < 0 ? 0 : (s >= N ? N - 1 : s);
    d = d < 0 ? 0 : (d >= N ? N - 1 : d);
    t = t < 0 ? 0 : (t > 4 ? 4 : t);
    int pos = atomicAdd(&cursor[d], 1);
    csr[pos] = (s << 3) | t;
}

// ============ fused GINE layer: gather-agg -> MLP, 128 rows/block, 512 threads ============
// (round-12 form: 4 rows lockstep per rp, k-unroll 2, conditional loads, LDS CSR cache)
__global__ __launch_bounds__(512, 4) void gine_kernel(
    const u16* __restrict__ x_in, u16* __restrict__ x_out,
    const int* __restrict__ types, int use_emb, const u16* __restrict__ ebf,
    const int* __restrict__ offs, const int* __restrict__ csr,
    const float* __restrict__ bond_emb,
    const u16* __restrict__ w1t, const float* __restrict__ b1,
    const u16* __restrict__ w2t, const float* __restrict__ b2, int N)
{
    __shared__ __align__(16) u16 As[128][136];   // A-tile, +8 pad
    __shared__ __align__(16) u16 Ws[128][136];   // W^T tile, +8 pad
    __shared__ __align__(16) u16 bsh[5 * 128];   // bond table bf16
    __shared__ __align__(16) int csh[CSH];       // CSR slice cache
    const int tid  = threadIdx.x;
    const int row0 = blockIdx.x * 128;
    const int wave = tid >> 6, lane = tid & 63;
    const int m = lane & 15, quad = lane >> 4;

    for (int i = tid; i < 640; i += 512) bsh[i] = f2bf(bond_emb[i]);
    // stage W1^T
    {
        const uint4* src = (const uint4*)w1t;
        for (int i = tid; i < 2048; i += 512) {
            int n = i >> 4, k8 = i & 15;
            *(uint4*)&Ws[n][k8 * 8] = src[i];
        }
    }
    // stage block's CSR slice (coalesced)
    const int rend = (row0 + 128 < N) ? row0 + 128 : N;
    const int e0 = offs[row0];
    {
        int cnt = offs[rend] - e0;
        cnt = cnt < CSH ? cnt : CSH;
        for (int i = tid; i < cnt; i += 512) csh[i] = csr[e0 + i];
    }
    // ---- gather-aggregate: 4 rows in lockstep per row-processor ----
    {
        const int rp = tid >> 4, c8 = (tid & 15) * 8;
        __syncthreads();   // bsh + csh visible

        int rowA = row0 + rp,      rowB = row0 + 32 + rp;
        int rowC = row0 + 64 + rp, rowD = row0 + 96 + rp;
        int rcA = rowA < N ? rowA : N - 1;
        int rcB = rowB < N ? rowB : N - 1;
        int rcC = rowC < N ? rowC : N - 1;
        int rcD = rowD < N ? rowD : N - 1;
        const u16 *spA, *spB, *spC, *spD;
        if (use_emb) {
            int tA = types[rcA]; tA = tA < 0 ? 0 : (tA > 119 ? 119 : tA);
            int tB = types[rcB]; tB = tB < 0 ? 0 : (tB > 119 ? 119 : tB);
            int tC = types[rcC]; tC = tC < 0 ? 0 : (tC > 119 ? 119 : tC);
            int tD = types[rcD]; tD = tD < 0 ? 0 : (tD > 119 ? 119 : tD);
            spA = ebf + (size_t)tA * 128; spB = ebf + (size_t)tB * 128;
            spC = ebf + (size_t)tC * 128; spD = ebf + (size_t)tD * 128;
        } else {
            spA = x_in + (size_t)rcA * 128; spB = x_in + (size_t)rcB * 128;
            spC = x_in + (size_t)rcC * 128; spD = x_in + (size_t)rcD * 128;
        }
        int jbA = offs[rcA], jeA = rowA < N ? offs[rcA + 1] : jbA;
        int jbB = offs[rcB], jeB = rowB < N ? offs[rcB + 1] : jbB;
        int jbC = offs[rcC], jeC = rowC < N ? offs[rcC + 1] : jbC;
        int jbD = offs[rcD], jeD = rowD < N ? offs[rcD + 1] : jbD;
        uint4 svA = *(const uint4*)(spA + c8);
        uint4 svB = *(const uint4*)(spB + c8);
        uint4 svC = *(const uint4*)(spC + c8);
        uint4 svD = *(const uint4*)(spD + c8);
        float accA[8], accB[8], accC[8], accD[8];
        {
            const u16* pA = (const u16*)&svA; const u16* pB = (const u16*)&svB;
            const u16* pC = (const u16*)&svC; const u16* pD = (const u16*)&svD;
#pragma unroll
            for (int i = 0; i < 8; i++) {
                accA[i] = bf2f(pA[i]); accB[i] = bf2f(pB[i]);
                accC[i] = bf2f(pC[i]); accD[i] = bf2f(pD[i]);
            }
        }
        int lbA = jbA - e0, lbB = jbB - e0, lbC = jbC - e0, lbD = jbD - e0;
        int dA = jeA - jbA, dB = jeB - jbB, dC = jeC - jbC, dD = jeD - jbD;
        int dmax = dA > dB ? dA : dB;
        dmax = dC > dmax ? dC : dmax;
        dmax = dD > dmax ? dD : dmax;
        for (int k = 0; k < dmax; k += 2) {
            bool a0 = k < dA,     a1 = (k + 1) < dA;
            bool a2 = k < dB,     a3 = (k + 1) < dB;
            bool a4 = k < dC,     a5 = (k + 1) < dC;
            bool a6 = k < dD,     a7 = (k + 1) < dD;
            int v0 = 0, v1 = 0, v2 = 0, v3 = 0, v4 = 0, v5 = 0, v6 = 0, v7 = 0;
            if (a0) { int li = lbA + k;     v0 = (li < CSH) ? csh[li] : csr[jbA + k]; }
            if (a1) { int li = lbA + k + 1; v1 = (li < CSH) ? csh[li] : csr[jbA + k + 1]; }
            if (a2) { int li = lbB + k;     v2 = (li < CSH) ? csh[li] : csr[jbB + k]; }
            if (a3) { int li = lbB + k + 1; v3 = (li < CSH) ? csh[li] : csr[jbB + k + 1]; }
            if (a4) { int li = lbC + k;     v4 = (li < CSH) ? csh[li] : csr[jbC + k]; }
            if (a5) { int li = lbC + k + 1; v5 = (li < CSH) ? csh[li] : csr[jbC + k + 1]; }
            if (a6) { int li = lbD + k;     v6 = (li < CSH) ? csh[li] : csr[jbD + k]; }
            if (a7) { int li = lbD + k + 1; v7 = (li < CSH) ? csh[li] : csr[jbD + k + 1]; }
            const u16 *p0, *p1, *p2, *p3, *p4, *p5, *p6, *p7;
            if (use_emb) {
                int t0 = types[v0 >> 3]; t0 = t0 < 0 ? 0 : (t0 > 119 ? 119 : t0);
                int t1 = types[v1 >> 3]; t1 = t1 < 0 ? 0 : (t1 > 119 ? 119 : t1);
                int t2 = types[v2 >> 3]; t2 = t2 < 0 ? 0 : (t2 > 119 ? 119 : t2);
                int t3 = types[v3 >> 3]; t3 = t3 < 0 ? 0 : (t3 > 119 ? 119 : t3);
                int t4 = types[v4 >> 3]; t4 = t4 < 0 ? 0 : (t4 > 119 ? 119 : t4);
                int t5 = types[v5 >> 3]; t5 = t5 < 0 ? 0 : (t5 > 119 ? 119 : t5);
                int t6 = types[v6 >> 3]; t6 = t6 < 0 ? 0 : (t6 > 119 ? 119 : t6);
                int t7 = types[v7 >> 3]; t7 = t7 < 0 ? 0 : (t7 > 119 ? 119 : t7);
                p0 = ebf + (size_t)t0 * 128; p1 = ebf + (size_t)t1 * 128;
                p2 = ebf + (size_t)t2 * 128; p3 = ebf + (size_t)t3 * 128;
                p4 = ebf + (size_t)t4 * 128; p5 = ebf + (size_t)t5 * 128;
                p6 = ebf + (size_t)t6 * 128; p7 = ebf + (size_t)t7 * 128;
            } else {
                p0 = x_in + (size_t)(v0 >> 3) * 128; p1 = x_in + (size_t)(v1 >> 3) * 128;
                p2 = x_in + (size_t)(v2 >> 3) * 128; p3 = x_in + (size_t)(v3 >> 3) * 128;
                p4 = x_in + (size_t)(v4 >> 3) * 128; p5 = x_in + (size_t)(v5 >> 3) * 128;
                p6 = x_in + (size_t)(v6 >> 3) * 128; p7 = x_in + (size_t)(v7 >> 3) * 128;
            }
            uint4 g0 = *(const uint4*)(p0 + c8);   // 8 independent gathers in flight
            uint4 g1 = *(const uint4*)(p1 + c8);
            uint4 g2 = *(const uint4*)(p2 + c8);
            uint4 g3 = *(const uint4*)(p3 + c8);
            uint4 g4 = *(const uint4*)(p4 + c8);
            uint4 g5 = *(const uint4*)(p5 + c8);
            uint4 g6 = *(const uint4*)(p6 + c8);
            uint4 g7 = *(const uint4*)(p7 + c8);
            if (a0) { const u16* gp = (const u16*)&g0; const u16* bp = bsh + (v0 & 7) * 128 + c8;
#pragma unroll
                for (int i = 0; i < 8; i++) { float mm = bf2f(gp[i]) + bf2f(bp[i]); accA[i] += mm > 0.f ? mm : 0.f; } }
            if (a1) { const u16* gp = (const u16*)&g1; const u16* bp = bsh + (v1 & 7) * 128 + c8;
#pragma unroll
                for (int i = 0; i < 8; i++) { float mm = bf2f(gp[i]) + bf2f(bp[i]); accA[i] += mm > 0.f ? mm : 0.f; } }
            if (a2) { const u16* gp = (const u16*)&g2; const u16* bp = bsh + (v2 & 7) * 128 + c8;
#pragma unroll
                for (int i = 0; i < 8; i++) { float mm = bf2f(gp[i]) + bf2f(bp[i]); accB[i] += mm > 0.f ? mm : 0.f; } }
            if (a3) { const u16* gp = (const u16*)&g3; const u16* bp = bsh + (v3 & 7) * 128 + c8;
#pragma unroll
                for (int i = 0; i < 8; i++) { float mm = bf2f(gp[i]) + bf2f(bp[i]); accB[i] += mm > 0.f ? mm : 0.f; } }
            if (a4) { const u16* gp = (const u16*)&g4; const u16* bp = bsh + (v4 & 7) * 128 + c8;
#pragma unroll
                for (int i = 0; i < 8; i++) { float mm = bf2f(gp[i]) + bf2f(bp[i]); accC[i] += mm > 0.f ? mm : 0.f; } }
            if (a5) { const u16* gp = (const u16*)&g5; const u16* bp = bsh + (v5 & 7) * 128 + c8;
#pragma unroll
                for (int i = 0; i < 8; i++) { float mm = bf2f(gp[i]) + bf2f(bp[i]); accC[i] += mm > 0.f ? mm : 0.f; } }
            if (a6) { const u16* gp = (const u16*)&g6; const u16* bp = bsh + (v6 & 7) * 128 + c8;
#pragma unroll
                for (int i = 0; i < 8; i++) { float mm = bf2f(gp[i]) + bf2f(bp[i]); accD[i] += mm > 0.f ? mm : 0.f; } }
            if (a7) { const u16* gp = (const u16*)&g7; const u16* bp = bsh + (v7 & 7) * 128 + c8;
#pragma unroll
                for (int i = 0; i < 8; i++) { float mm = bf2f(gp[i]) + bf2f(bp[i]); accD[i] += mm > 0.f ? mm : 0.f; } }
        }
        uint4 ovA = make_uint4(0u,0u,0u,0u), ovB = ovA, ovC = ovA, ovD = ovA;
        if (rowA < N) { u16* op = (u16*)&ovA;
#pragma unroll
            for (int i = 0; i < 8; i++) op[i] = f2bf(accA[i]); }
        if (rowB < N) { u16* op = (u16*)&ovB;
#pragma unroll
            for (int i = 0; i < 8; i++) op[i] = f2bf(accB[i]); }
        if (rowC < N) { u16* op = (u16*)&ovC;
#pragma unroll
            for (int i = 0; i < 8; i++) op[i] = f2bf(accC[i]); }
        if (rowD < N) { u16* op = (u16*)&ovD;
#pragma unroll
            for (int i = 0; i < 8; i++) op[i] = f2bf(accD[i]); }
        *(uint4*)&As[rp][c8]      = ovA;
        *(uint4*)&As[32 + rp][c8] = ovB;
        *(uint4*)&As[64 + rp][c8] = ovC;
        *(uint4*)&As[96 + rp][c8] = ovD;
    }
    __syncthreads();

    // mm1: each of 8 waves does 16 rows x 128 cols
    f32x4 acc[8];
#pragma unroll
    for (int c = 0; c < 8; c++) acc[c] = (f32x4){0.f, 0.f, 0.f, 0.f};
#pragma unroll
    for (int q = 0; q < 4; q++) {
        short8 a = *(const short8*)&As[wave * 16 + m][q * 32 + quad * 8];
#pragma unroll
        for (int c = 0; c < 8; c++) {
            short8 b = *(const short8*)&Ws[c * 16 + m][q * 32 + quad * 8];
            acc[c] = __builtin_amdgcn_mfma_f32_16x16x32_bf16(a, b, acc[c], 0, 0, 0);
        }
    }
    __syncthreads();
    // stage W2^T
    {
        const uint4* src = (const uint4*)w2t;
        for (int i = tid; i < 2048; i += 512) {
            int n = i >> 4, k8 = i & 15;
            *(uint4*)&Ws[n][k8 * 8] = src[i];
        }
    }
    // h = relu(acc+b1) -> As  (D layout: row=quad*4+r, col=lane&15)
#pragma unroll
    for (int c = 0; c < 8; c++) {
        int col = c * 16 + m;
        float bias = b1[col];
#pragma unroll
        for (int r = 0; r < 4; r++) {
            float v = acc[c][r] + bias;
            v = v > 0.f ? v : 0.f;
            As[wave * 16 + quad * 4 + r][col] = f2bf(v);
        }
    }
    __syncthreads();
    // mm2
    f32x4 acc2[8];
#pragma unroll
    for (int c = 0; c < 8; c++) acc2[c] = (f32x4){0.f, 0.f, 0.f, 0.f};
#pragma unroll
    for (int q = 0; q < 4; q++) {
        short8 a = *(const short8*)&As[wave * 16 + m][q * 32 + quad * 8];
#pragma unroll
        for (int c = 0; c < 8; c++) {
            short8 b = *(const short8*)&Ws[c * 16 + m][q * 32 + quad * 8];
            acc2[c] = __builtin_amdgcn_mfma_f32_16x16x32_bf16(a, b, acc2[c], 0, 0, 0);
        }
    }
    __syncthreads();
#pragma unroll
    for (int c = 0; c < 8; c++) {
        int col = c * 16 + m;
        float bias = b2[col];
#pragma unroll
        for (int r = 0; r < 4; r++)
            As[wave * 16 + quad * 4 + r][col] = f2bf(acc2[c][r] + bias);
    }
    __syncthreads();
    for (int i = tid; i < 2048; i += 512) {
        int r = i >> 4, c8 = (i & 15) * 8;
        int row = row0 + r;
        if (row < N) *(uint4*)(x_out + (size_t)row * 128 + c8) = *(const uint4*)&As[r][c8];
    }
}

// ---- readout mean: gm[g] = bf16(mean of x rows in segment g); bounds precomputed
__global__ __launch_bounds__(256) void readout_mean_kernel(
    const u16* __restrict__ x, const int* __restrict__ gbounds,
    u16* __restrict__ gm, int N)
{
    __shared__ float part[16][128];
    int b = blockIdx.x;
    int tid = threadIdx.x;
    int s = gbounds[b], e = gbounds[b + 1];
    int rg = tid >> 4, c8 = (tid & 15) * 8;
    float acc[8];
#pragma unroll
    for (int i = 0; i < 8; i++) acc[i] = 0.f;
    for (int n = s + rg; n < e; n += 16) {
        uint4 v = *(const uint4*)(x + (size_t)n * 128 + c8);
        const u16* vp = (const u16*)&v;
#pragma unroll
        for (int i = 0; i < 8; i++) acc[i] += bf2f(vp[i]);
    }
#pragma unroll
    for (int i = 0; i < 8; i++) part[rg][c8 + i] = acc[i];
    __syncthreads();
    if (tid < 128) {
        float sum = 0.f;
#pragma unroll
        for (int g = 0; g < 16; g++) sum += part[g][tid];
        float cnt = (float)((e - s) > 0 ? (e - s) : 1);
        gm[(size_t)b * 128 + tid] = f2bf(sum / cnt);
    }
}

// ---- proj: out = silu(gm @ PW1 + pb1) @ PW2 + pb2   (fp32 out, 64 rows/block)
__global__ __launch_bounds__(256) void proj_kernel(
    const u16* __restrict__ gm, float* __restrict__ out,
    const u16* __restrict__ pw1t, const float* __restrict__ pb1,
    const u16* __restrict__ pw2t, const float* __restrict__ pb2, int G)
{
    __shared__ __align__(16) u16 As[64][136];
    __shared__ __align__(16) u16 Ws[128][136];
    const int tid  = threadIdx.x;
    const int row0 = blockIdx.x * 64;
    const int wave = tid >> 6, lane = tid & 63;
    const int m = lane & 15, quad = lane >> 4;

    {
        const uint4* src = (const uint4*)pw1t;
        for (int i = tid; i < 2048; i += 256) {
            int n = i >> 4, k8 = i & 15;
            *(uint4*)&Ws[n][k8 * 8] = src[i];
        }
    }
    for (int i = tid; i < 1024; i += 256) {
        int r = i >> 4, c8 = (i & 15) * 8;
        int row = row0 + r;
        uint4 ov = make_uint4(0u, 0u, 0u, 0u);
        if (row < G) ov = *(const uint4*)(gm + (size_t)row * 128 + c8);
        *(uint4*)&As[r][c8] = ov;
    }
    __syncthreads();
    f32x4 acc[8];
#pragma unroll
    for (int c = 0; c < 8; c++) acc[c] = (f32x4){0.f, 0.f, 0.f, 0.f};
#pragma unroll
    for (int q = 0; q < 4; q++) {
        short8 a = *(const short8*)&As[wave * 16 + m][q * 32 + quad * 8];
#pragma unroll
        for (int c = 0; c < 8; c++) {
            short8 b = *(const short8*)&Ws[c * 16 + m][q * 32 + quad * 8];
            acc[c] = __builtin_amdgcn_mfma_f32_16x16x32_bf16(a, b, acc[c], 0, 0, 0);
        }
    }
    __syncthreads();
    {
        const uint4* src = (const uint4*)pw2t;
        for (int i = tid; i < 2048; i += 256) {
            int n = i >> 4, k8 = i & 15;
            *(uint4*)&Ws[n][k8 * 8] = src[i];
        }
    }
#pragma unroll
    for (int c = 0; c < 8; c++) {
        int col = c * 16 + m;
        float bias = pb1[col];
#pragma unroll
        for (int r = 0; r < 4; r++) {
            float v = acc[c][r] + bias;
            v = v / (1.f + __expf(-v));   // SiLU
            As[wave * 16 + quad * 4 + r][col] = f2bf(v);
        }
    }
    __syncthreads();
    f32x4 acc2[8];
#pragma unroll
    for (int c = 0; c < 8; c++) acc2[c] = (f32x4){0.f, 0.f, 0.f, 0.f};
#pragma unroll
    for (int q = 0; q < 4; q++) {
        short8 a = *(const short8*)&As[wave * 16 + m][q * 32 + quad * 8];
#pragma unroll
        for (int c = 0; c < 8; c++) {
            short8 b = *(const short8*)&Ws[c * 16 + m][q * 32 + quad * 8];
            acc2[c] = __builtin_amdgcn_mfma_f32_16x16x32_bf16(a, b, acc2[c], 0, 0, 0);
        }
    }
#pragma unroll
    for (int c = 0; c < 8; c++) {
        int col = c * 16 + m;
        float bias = pb2[col];
#pragma unroll
        for (int r = 0; r < 4; r++) {
            int row = row0 + wave * 16 + quad * 4 + r;
            if (row < G) out[(size_t)row * 128 + col] = acc2[c][r] + bias;
        }
    }
}

extern "C" void kernel_launch(void* const* d_in, const int* in_sizes, int n_in,
                              void* d_out, int out_size, void* d_ws, size_t ws_size,
                              hipStream_t stream) {
    const int*   atom_types  = (const int*)d_in[0];
    const int*   edges       = (const int*)d_in[1];
    const int*   edge_types  = (const int*)d_in[2];
    const int*   node_batch  = (const int*)d_in[3];
    const float* atom_emb    = (const float*)d_in[4];
    const float* bond_emb    = (const float*)d_in[5];
    const float* conv_w1     = (const float*)d_in[6];
    const float* conv_b1     = (const float*)d_in[7];
    const float* conv_w2     = (const float*)d_in[8];
    const float* conv_b2     = (const float*)d_in[9];
    const float* pw1         = (const float*)d_in[10];
    const float* pb1         = (const float*)d_in[11];
    const float* pw2         = (const float*)d_in[12];
    const float* pb2         = (const float*)d_in[13];
    float* out = (float*)d_out;

    const int N = in_sizes[0];
    const int E = in_sizes[2];
    const int G = out_size / HDIM;
    const int nblk = (N + SCAN_B - 1) / SCAN_B;

    size_t xA_bytes  = (size_t)N * HDIM * sizeof(u16);
    size_t xB_bytes  = (size_t)N * HDIM * sizeof(u16);
    size_t wt_bytes  = (size_t)8 * HDIM * HDIM * sizeof(u16);
    size_t ebf_bytes = (size_t)120 * HDIM * sizeof(u16);
    size_t gm_bytes  = (size_t)G * HDIM * sizeof(u16);
    size_t deg_bytes = (size_t)N * 4;
    size_t off_bytes = (size_t)(N + 1) * 4;
    size_t cur_bytes = (size_t)N * 4;
    size_t bs_bytes  = (size_t)nblk * 4;
    size_t gb_bytes  = (size_t)(G + 1) * 4;
    size_t csr_bytes = (size_t)E * 4;
    size_t need = xA_bytes + xB_bytes + wt_bytes + ebf_bytes + gm_bytes +
                  deg_bytes + off_bytes + cur_bytes + bs_bytes + gb_bytes + csr_bytes;
    if (ws_size < need) {
        hipMemsetAsync(d_out, 0, (size_t)out_size * sizeof(float), stream);
        return;
    }
    char* p = (char*)d_ws;
    u16* xA     = (u16*)p;  p += xA_bytes;
    u16* xB     = (u16*)p;  p += xB_bytes;
    u16* wt     = (u16*)p;  p += wt_bytes;
    u16* ebf    = (u16*)p;  p += ebf_bytes;
    u16* gm     = (u16*)p;  p += gm_bytes;
    int* deg    = (int*)p;  p += deg_bytes;
    int* offs   = (int*)p;  p += off_bytes;
    int* cur    = (int*)p;  p += cur_bytes;
    int* bsum   = (int*)p;  p += bs_bytes;
    int* gbound = (int*)p;  p += gb_bytes;
    int* csr    = (int*)p;

    hipMemsetAsync(deg, 0, deg_bytes, stream);
    prep_hist_kernel<<<PREP_BLOCKS + (E + 255) / 256, 256, 0, stream>>>(
        conv_w1, conv_w2, pw1, pw2, atom_emb, wt, ebf, edges, deg, E, N);
    scan_block_kernel<<<nblk, SCAN_B, 0, stream>>>(deg, offs, bsum, N);
    finalize_offs_kernel<<<(N + 255) / 256, 256, 0, stream>>>(
        offs, bsum, cur, node_batch, gbound, N, E, G);
    fill_csr_kernel<<<(E + 255) / 256, 256, 0, stream>>>(edges, edge_types, cur, csr, E, N);

    const int gblocks = (N + 127) / 128;
    gine_kernel<<<gblocks, 512, 0, stream>>>(
        xB /*unused*/, xA, atom_types, 1, ebf, offs, csr, bond_emb,
        wt + 0 * 16384, conv_b1 + 0, wt + 3 * 16384, conv_b2 + 0, N);
    gine_kernel<<<gblocks, 512, 0, stream>>>(
        xA, xB, atom_types, 0, ebf, offs, csr, bond_emb,
        wt + 1 * 16384, conv_b1 + 128, wt + 4 * 16384, conv_b2 + 128, N);
    gine_kernel<<<gblocks, 512, 0, stream>>>(
        xB, xA, atom_types, 0, ebf, offs, csr, bond_emb,
        wt + 2 * 16384, conv_b1 + 256, wt + 5 * 16384, conv_b2 + 256, N);

    readout_mean_kernel<<<G, 256, 0, stream>>>(xA, gbound, gm, N);
    proj_kernel<<<(G + 63) / 64, 256, 0, stream>>>(
        gm, out, wt + 6 * 16384, pb1, wt + 7 * 16384, pb2, G);
}